// Round 4
// baseline (174.907 us; speedup 1.0000x reference)
//
#include <hip/hip_runtime.h>

#define NB 4
#define SLQ 256
#define SLK 256
#define DD 768

// tanh(x) = 1 - 2/(1+e^{2x});  e^{2(q+k)} = exp2(q*2log2e)*exp2(k*2log2e).
// Softmax-invariant constants (sum Ws + bs) dropped from the logits.
#define TWO_LOG2E 2.8853900817779268f
#define LOG2E 1.4426950408889634f

typedef _Float16 f16x4 __attribute__((ext_vector_type(4)));
typedef _Float16 f16x8 __attribute__((ext_vector_type(8)));
typedef float f32x4 __attribute__((ext_vector_type(4)));

__device__ __forceinline__ float fexp2(float x) { return __builtin_amdgcn_exp2f(x); }
__device__ __forceinline__ float frcp(float x) { return __builtin_amdgcn_rcpf(x); }

// LDS row stride in halves for MFMA tiles (BK=32 + 8 pad): 80B/row -> frag
// reads hit 8 distinct 16B bank-groups per 8 rows, 2-way max (free).
#define LSTR 40

// ---------------- Prep 1: convert q/k/v inputs fp32 -> fp16 ----------------
__global__ __launch_bounds__(256) void prep_a_kernel(
    const float* __restrict__ q, const float* __restrict__ k,
    const float* __restrict__ v, _Float16* __restrict__ qh,
    _Float16* __restrict__ kh, _Float16* __restrict__ vh)
{
    const int z = blockIdx.z;
    const float* src = (z == 0) ? q : (z == 1) ? k : v;
    _Float16* dst = (z == 0) ? qh : (z == 1) ? kh : vh;
    const int i8 = (blockIdx.x * 256 + threadIdx.x) * 8;
    float4 a = *(const float4*)&src[i8];
    float4 b = *(const float4*)&src[i8 + 4];
    f16x8 h;
    h[0] = (_Float16)a.x; h[1] = (_Float16)a.y; h[2] = (_Float16)a.z; h[3] = (_Float16)a.w;
    h[4] = (_Float16)b.x; h[5] = (_Float16)b.y; h[6] = (_Float16)b.z; h[7] = (_Float16)b.w;
    *(f16x8*)&dst[i8] = h;
}

// ---------------- Prep 2: W [in][out] fp32 -> Wt [out][in] fp16 ----------------
__global__ __launch_bounds__(256) void prep_wt_kernel(
    const float* __restrict__ Wq, const float* __restrict__ Wk,
    const float* __restrict__ Wv, _Float16* __restrict__ wtq,
    _Float16* __restrict__ wtk, _Float16* __restrict__ wtv)
{
    const int z = blockIdx.z;
    const float* W = (z == 0) ? Wq : (z == 1) ? Wk : Wv;
    _Float16* Wt = (z == 0) ? wtq : (z == 1) ? wtk : wtv;

    __shared__ float t[64][65];
    const int tid = threadIdx.x;
    const int kt0 = blockIdx.y * 64;  // in-dim
    const int nt0 = blockIdx.x * 64;  // out-dim

    const int col4 = (tid & 15) << 2;
#pragma unroll
    for (int i = 0; i < 4; ++i) {
        const int row = ((tid >> 4) << 2) + i;
        *(float4*)&t[row][col4] = *(const float4*)&W[(size_t)(kt0 + row) * DD + nt0 + col4];
    }
    __syncthreads();
    const int n = tid >> 2;
    const int k16 = (tid & 3) << 4;
    f16x8 h0, h1;
#pragma unroll
    for (int j = 0; j < 8; ++j) {
        h0[j] = (_Float16)t[k16 + j][n];
        h1[j] = (_Float16)t[k16 + 8 + j][n];
    }
    *(f16x8*)&Wt[(size_t)(nt0 + n) * DD + kt0 + k16] = h0;
    *(f16x8*)&Wt[(size_t)(nt0 + n) * DD + kt0 + k16 + 8] = h1;
}

// ---------------- QKV projection, fp16 MFMA, clean staging ----------------
// C = A @ Wt^T + bias. A:[1024x768] f16, Wt:[768(out)x768(in)] f16.
// z=0 -> eq fp32 = exp2(q*2log2e); z=1 -> ekh f16 likewise; z=2 -> v f16 TRANSPOSED
// per batch: vsht[b][col(768)][row(256)] for the attended GEMM's B-side.
__global__ __launch_bounds__(256) void qkv_f16_kernel(
    const _Float16* __restrict__ qh, const _Float16* __restrict__ kh,
    const _Float16* __restrict__ vh, const _Float16* __restrict__ wtq,
    const _Float16* __restrict__ wtk, const _Float16* __restrict__ wtv,
    const float* __restrict__ bq, const float* __restrict__ bk,
    const float* __restrict__ bv, float* __restrict__ eq,
    _Float16* __restrict__ ekh, _Float16* __restrict__ vsht)
{
    const int z = blockIdx.z;
    const _Float16* A = (z == 0) ? qh : (z == 1) ? kh : vh;
    const _Float16* Wt = (z == 0) ? wtq : (z == 1) ? wtk : wtv;
    const float* bias = (z == 0) ? bq : (z == 1) ? bk : bv;

    __shared__ _Float16 Ah[64 * LSTR]; // [m][k]
    __shared__ _Float16 Bh[64 * LSTR]; // [n][k]

    const int tid = threadIdx.x;
    const int lane = tid & 63;
    const int wid = tid >> 6;
    const int wr = wid >> 1;
    const int wc = wid & 1;
    const int row0 = blockIdx.y * 64;
    const int col0 = blockIdx.x * 64;

    const int sr = tid >> 2;         // staged row 0..63
    const int sc = (tid & 3) << 3;   // k-offset 0,8,16,24

    const _Float16* Ap = A + (size_t)(row0 + sr) * DD + sc;
    const _Float16* Bp = Wt + (size_t)(col0 + sr) * DD + sc;

    f16x8 pa = *(const f16x8*)Ap;
    f16x8 pb = *(const f16x8*)Bp;

    f32x4 acc[2][2] = {};
    const int kj = (lane >> 4) << 3;
    const int fr = lane & 15;

    for (int s = 0; s < DD / 32; ++s) {
        __syncthreads();
        *(f16x8*)&Ah[sr * LSTR + sc] = pa;
        *(f16x8*)&Bh[sr * LSTR + sc] = pb;
        __syncthreads();
        if (s + 1 < DD / 32) {
            pa = *(const f16x8*)(Ap + (s + 1) * 32);
            pb = *(const f16x8*)(Bp + (s + 1) * 32);
        }
        f16x8 af0 = *(const f16x8*)&Ah[(wr * 32 + fr) * LSTR + kj];
        f16x8 af1 = *(const f16x8*)&Ah[(wr * 32 + 16 + fr) * LSTR + kj];
        f16x8 bf0 = *(const f16x8*)&Bh[(wc * 32 + fr) * LSTR + kj];
        f16x8 bf1 = *(const f16x8*)&Bh[(wc * 32 + 16 + fr) * LSTR + kj];
        acc[0][0] = __builtin_amdgcn_mfma_f32_16x16x32_f16(af0, bf0, acc[0][0], 0, 0, 0);
        acc[0][1] = __builtin_amdgcn_mfma_f32_16x16x32_f16(af0, bf1, acc[0][1], 0, 0, 0);
        acc[1][0] = __builtin_amdgcn_mfma_f32_16x16x32_f16(af1, bf0, acc[1][0], 0, 0, 0);
        acc[1][1] = __builtin_amdgcn_mfma_f32_16x16x32_f16(af1, bf1, acc[1][1], 0, 0, 0);
    }

    // C/D layout: col = lane&15, row = (lane>>4)*4 + reg [m89 verified]
    const int colb = col0 + wc * 32 + fr;
    const int rowb = row0 + wr * 32 + ((lane >> 4) << 2);
#pragma unroll
    for (int mf = 0; mf < 2; ++mf) {
#pragma unroll
        for (int nf = 0; nf < 2; ++nf) {
            const int col = colb + nf * 16;
            const float bvv = bias[col];
#pragma unroll
            for (int r = 0; r < 4; ++r) {
                const int row = rowb + mf * 16 + r;
                const float val = acc[mf][nf][r] + bvv;
                if (z == 0) {
                    eq[(size_t)row * DD + col] = fexp2(fminf(val * TWO_LOG2E, 15.0f));
                } else if (z == 1) {
                    ekh[(size_t)row * DD + col] =
                        (_Float16)fexp2(fminf(val * TWO_LOG2E, 15.0f));
                } else {
                    vsht[((size_t)(row >> 8) * DD + col) * SLK + (row & 255)] =
                        (_Float16)val;
                }
            }
        }
    }
}

// ---------------- Fused scores + softmax ----------------
// Block = one q-row (256 threads = 256 k). logit = -2 sum_d Ws_d*rcp(1+Eq*Ek);
// block-softmax; write P fp32 (output) and fp16 (for attended). 1024 blocks.
__global__ __launch_bounds__(256) void scores_softmax_kernel(
    const float* __restrict__ Eq, const _Float16* __restrict__ Ekh,
    const float* __restrict__ Ws, float* __restrict__ attnw,
    _Float16* __restrict__ phalf)
{
    const int qrow = blockIdx.x;          // 0..255
    const int b = blockIdx.y;             // 0..3
    const int tid = threadIdx.x;          // k
    const int lane = tid & 63;
    const int w = tid >> 6;

    const _Float16* kr = Ekh + (size_t)(b * SLK + tid) * DD;
    const float* qp = Eq + (size_t)(b * SLQ + qrow) * DD;   // block-uniform
    // Ws block-uniform

    float acc0 = 0.f, acc1 = 0.f, acc2 = 0.f, acc3 = 0.f;

    f16x8 e0 = *(const f16x8*)kr;
    f16x8 e1 = *(const f16x8*)(kr + 8);
    float g[16], wv[16], gn[16], wn[16];
#pragma unroll
    for (int j = 0; j < 16; ++j) { g[j] = qp[j]; wv[j] = Ws[j]; }

    for (int c = 0; c < DD / 16; ++c) {
        f16x8 en0, en1;
        const int dn = (c + 1) * 16;
        if (c + 1 < DD / 16) {
            en0 = *(const f16x8*)(kr + dn);
            en1 = *(const f16x8*)(kr + dn + 8);
#pragma unroll
            for (int j = 0; j < 16; ++j) { gn[j] = qp[dn + j]; wn[j] = Ws[dn + j]; }
        }
#pragma unroll
        for (int j = 0; j < 8; ++j) {
            const float ea = (float)e0[j];
            const float eb = (float)e1[j];
            acc0 = fmaf(wv[j], frcp(fmaf(g[j], ea, 1.0f)), acc0);
            acc1 = fmaf(wv[j + 8], frcp(fmaf(g[j + 8], eb, 1.0f)), acc1);
        }
        e0 = en0; e1 = en1;
#pragma unroll
        for (int j = 0; j < 16; ++j) { g[j] = gn[j]; wv[j] = wn[j]; }
    }

    const float logit = -2.0f * ((acc0 + acc1) + (acc2 + acc3));

    __shared__ float redm[4], reds[4];
    float m = logit;
#pragma unroll
    for (int off = 32; off; off >>= 1) m = fmaxf(m, __shfl_xor(m, off, 64));
    if (lane == 0) redm[w] = m;
    __syncthreads();
    m = fmaxf(fmaxf(redm[0], redm[1]), fmaxf(redm[2], redm[3]));

    const float ex = fexp2((logit - m) * LOG2E);
    float s = ex;
#pragma unroll
    for (int off = 32; off; off >>= 1) s += __shfl_xor(s, off, 64);
    if (lane == 0) reds[w] = s;
    __syncthreads();
    s = (reds[0] + reds[1]) + (reds[2] + reds[3]);

    const float p = ex * (1.0f / s);
    const size_t o = (size_t)(b * SLQ + qrow) * SLK + tid;
    attnw[o] = p;
    phalf[o] = (_Float16)p;
}

// ---------------- Attended: out[b] = P (256x256) @ V (256x768), fp16 MFMA ----------------
// B-side reads vsht [out-col][k] -> contiguous along k, same staging as qkv.
__global__ __launch_bounds__(256) void attended_f16_kernel(
    const _Float16* __restrict__ phalf, const _Float16* __restrict__ vsht,
    float* __restrict__ out)
{
    const int b = blockIdx.z;
    const _Float16* A = phalf + (size_t)b * SLQ * SLK;
    const _Float16* Bt = vsht + (size_t)b * DD * SLK;
    float* C = out + (size_t)b * SLQ * DD;

    __shared__ _Float16 Ah[64 * LSTR];
    __shared__ _Float16 Bh[64 * LSTR];

    const int tid = threadIdx.x;
    const int lane = tid & 63;
    const int wid = tid >> 6;
    const int wr = wid >> 1;
    const int wc = wid & 1;
    const int row0 = blockIdx.y * 64;
    const int col0 = blockIdx.x * 64;

    const int sr = tid >> 2;
    const int sc = (tid & 3) << 3;

    const _Float16* Ap = A + (size_t)(row0 + sr) * SLK + sc;
    const _Float16* Bp = Bt + (size_t)(col0 + sr) * SLK + sc;

    f16x8 pa = *(const f16x8*)Ap;
    f16x8 pb = *(const f16x8*)Bp;

    f32x4 acc[2][2] = {};
    const int kj = (lane >> 4) << 3;
    const int fr = lane & 15;

    for (int s = 0; s < SLK / 32; ++s) {
        __syncthreads();
        *(f16x8*)&Ah[sr * LSTR + sc] = pa;
        *(f16x8*)&Bh[sr * LSTR + sc] = pb;
        __syncthreads();
        if (s + 1 < SLK / 32) {
            pa = *(const f16x8*)(Ap + (s + 1) * 32);
            pb = *(const f16x8*)(Bp + (s + 1) * 32);
        }
        f16x8 af0 = *(const f16x8*)&Ah[(wr * 32 + fr) * LSTR + kj];
        f16x8 af1 = *(const f16x8*)&Ah[(wr * 32 + 16 + fr) * LSTR + kj];
        f16x8 bf0 = *(const f16x8*)&Bh[(wc * 32 + fr) * LSTR + kj];
        f16x8 bf1 = *(const f16x8*)&Bh[(wc * 32 + 16 + fr) * LSTR + kj];
        acc[0][0] = __builtin_amdgcn_mfma_f32_16x16x32_f16(af0, bf0, acc[0][0], 0, 0, 0);
        acc[0][1] = __builtin_amdgcn_mfma_f32_16x16x32_f16(af0, bf1, acc[0][1], 0, 0, 0);
        acc[1][0] = __builtin_amdgcn_mfma_f32_16x16x32_f16(af1, bf0, acc[1][0], 0, 0, 0);
        acc[1][1] = __builtin_amdgcn_mfma_f32_16x16x32_f16(af1, bf1, acc[1][1], 0, 0, 0);
    }

    const int colb = col0 + wc * 32 + fr;
    const int rowb = row0 + wr * 32 + ((lane >> 4) << 2);
#pragma unroll
    for (int mf = 0; mf < 2; ++mf)
#pragma unroll
        for (int nf = 0; nf < 2; ++nf)
#pragma unroll
            for (int r = 0; r < 4; ++r)
                C[(size_t)(rowb + mf * 16 + r) * DD + colb + nf * 16] = acc[mf][nf][r];
}

extern "C" void kernel_launch(void* const* d_in, const int* in_sizes, int n_in,
                              void* d_out, int out_size, void* d_ws, size_t ws_size,
                              hipStream_t stream)
{
    (void)in_sizes; (void)n_in; (void)out_size; (void)ws_size;

    const float* query = (const float*)d_in[0];
    const float* key   = (const float*)d_in[1];
    const float* value = (const float*)d_in[2];
    const float* Wq = (const float*)d_in[3];
    const float* bq = (const float*)d_in[4];
    const float* Wk = (const float*)d_in[5];
    const float* bk = (const float*)d_in[6];
    const float* Wv = (const float*)d_in[7];
    const float* bv = (const float*)d_in[8];
    const float* Ws = (const float*)d_in[9];
    // d_in[10] (bs): softmax-invariant shift, unused.

    const size_t NE = (size_t)NB * SLQ * DD;   // 786432
    const size_t NW = (size_t)DD * DD;         // 589824

    char* w = (char*)d_ws;
    float* eq = (float*)w;               w += NE * 4;
    _Float16* ekh = (_Float16*)w;        w += NE * 2;
    _Float16* vsht = (_Float16*)w;       w += NE * 2;
    _Float16* phalf = (_Float16*)w;      w += (size_t)NB * SLQ * SLK * 2;
    _Float16* qh = (_Float16*)w;         w += NE * 2;
    _Float16* kh = (_Float16*)w;         w += NE * 2;
    _Float16* vh = (_Float16*)w;         w += NE * 2;
    _Float16* wtq = (_Float16*)w;        w += NW * 2;
    _Float16* wtk = (_Float16*)w;        w += NW * 2;
    _Float16* wtv = (_Float16*)w;        // total ~14.4 MB

    float* out = (float*)d_out;
    float* attended = out;               // [4,256,768]
    float* attnw = out + NE;             // [4,256,256]

    prep_a_kernel<<<dim3(NE / (256 * 8), 1, 3), 256, 0, stream>>>(
        query, key, value, qh, kh, vh);
    prep_wt_kernel<<<dim3(DD / 64, DD / 64, 3), 256, 0, stream>>>(
        Wq, Wk, Wv, wtq, wtk, wtv);
    qkv_f16_kernel<<<dim3(DD / 64, (NB * SLQ) / 64, 3), 256, 0, stream>>>(
        qh, kh, vh, wtq, wtk, wtv, bq, bk, bv, eq, ekh, vsht);
    scores_softmax_kernel<<<dim3(SLQ, NB), 256, 0, stream>>>(eq, ekh, Ws, attnw, phalf);
    attended_f16_kernel<<<dim3(DD / 64, SLQ / 64, NB), 256, 0, stream>>>(
        phalf, vsht, attended);
}